// Round 15
// baseline (273.600 us; speedup 1.0000x reference)
//
#include <hip/hip_runtime.h>
#include <hip/hip_bf16.h>
#include <stdint.h>

typedef unsigned short u16;
typedef short short8 __attribute__((ext_vector_type(8)));
typedef short short4v __attribute__((ext_vector_type(4)));
typedef float f32x4 __attribute__((ext_vector_type(4)));

// scale folded into exp2: (1/sqrt(128)) * log2(e)
#define CSL (0.08838834764831845f * 1.4426950408889634f)
#define NEGR -1.0e13f   // raw-score mask value; *CSL -> -1.27e12 -> exp2 -> exactly 0

// B=2, S=2048, D=2048, H=16, DH=128.  M = B*S = 4096, N3 = 3*D = 6144, K = 2048.

__device__ __forceinline__ u16 f2b(float f) {
  union { float f; unsigned int u; } c; c.f = f;
  unsigned int u = c.u;
  u += 0x7fffu + ((u >> 16) & 1u);   // RNE; inputs are finite
  return (u16)(u >> 16);
}
__device__ __forceinline__ float b2f(u16 h) {
  union { float f; unsigned int u; } c; c.u = ((unsigned int)h) << 16;
  return c.f;
}

// ---------------- cast query f32 -> bf16 ----------------
__global__ __launch_bounds__(256) void k_cast_q(const float* __restrict__ in, u16* __restrict__ out) {
  size_t idx = ((size_t)blockIdx.x * 256 + threadIdx.x) * 8;
  float4 f0 = *(const float4*)(in + idx);
  float4 f1 = *(const float4*)(in + idx + 4);
  short8 o;
  o[0] = (short)f2b(f0.x); o[1] = (short)f2b(f0.y); o[2] = (short)f2b(f0.z); o[3] = (short)f2b(f0.w);
  o[4] = (short)f2b(f1.x); o[5] = (short)f2b(f1.y); o[6] = (short)f2b(f1.z); o[7] = (short)f2b(f1.w);
  *(short8*)(out + idx) = o;
}

// ---------------- transpose-cast W [2048][6144] f32 -> Wt [6144][2048] bf16 ----------------
__global__ __launch_bounds__(256) void k_cast_wt(const float* __restrict__ W, u16* __restrict__ Wt) {
  __shared__ u16 L[64 * 68];
  const int t = threadIdx.x;
  const int nb = blockIdx.x * 64;  // n base (0..6143)
  const int kb = blockIdx.y * 64;  // k base (0..2047)
#pragma unroll
  for (int it = 0; it < 4; ++it) {
    int idx = it * 1024 + t * 4;
    int r = idx >> 6, c = idx & 63;
    float4 f = *(const float4*)(W + (size_t)(kb + r) * 6144 + nb + c);
    L[r * 68 + c + 0] = f2b(f.x);
    L[r * 68 + c + 1] = f2b(f.y);
    L[r * 68 + c + 2] = f2b(f.z);
    L[r * 68 + c + 3] = f2b(f.w);
  }
  __syncthreads();
#pragma unroll
  for (int it = 0; it < 4; ++it) {
    int idx = it * 1024 + t * 4;
    int i = idx >> 6, j = idx & 63;
    short4v o;
#pragma unroll
    for (int e = 0; e < 4; ++e) o[e] = (short)L[(j + e) * 68 + i];
    *(short4v*)(Wt + (size_t)(nb + i) * 2048 + kb + j) = o;
  }
}

// ---------------- QKV GEMM, 256x192, counted-vmcnt pipeline (exact R12 revert: best 124 us) ----------------
// 512 thr = 8 waves (2M x 4N -> wave tile 128x48), BK=64, LDS 112 KiB dbuf, 512 blocks = 2 rounds.
// Supertile XCD map + T2 swizzle (verified: FETCH ~90 MB, conflicts 0).
// T4: S1={A p0,p2 + B p0-2} (5 loads -> P1), S2={A p1,p3} (2 loads -> P2).
// vmcnt(2) before P1 (drain S1(kt), keep S2(kt)); vmcnt(5) before P2 (drain S2(kt), keep S1(kt+1)).
__global__ __launch_bounds__(512, 1) void k_gemm256(const u16* __restrict__ A,
                                                    const u16* __restrict__ Bt,
                                                    const float* __restrict__ bias,
                                                    u16* __restrict__ qb,
                                                    u16* __restrict__ kbuf,
                                                    u16* __restrict__ vbuf) {
  __shared__ u16 As[2][16384];   // [dbuf][256 rows x 64 el], swizzled
  __shared__ u16 Bs[2][12288];   // [dbuf][192 rows x 64 el], swizzled
  const int t = threadIdx.x;
  const int ln = t & 63, w = t >> 6;
  const int lr = ln & 15, lg = ln >> 4;
  const int wm = w >> 2, wn = w & 3;           // 2 x 4 wave grid
  const int Lid = blockIdx.x;                  // 0..511
  const int xcd = Lid & 7, l = Lid >> 3;       // 64 blocks per XCD
  const int mt = (xcd & 1) * 8 + (l & 7);      // supertile: 8m x 8n, m-fastest
  const int nt = (xcd >> 1) * 8 + (l >> 3);
  const int mb = mt * 256, nb = nt * 192;
  const int cswz = (lr & 7) * 8;               // read-side swizzle (elem)
  const int srow = w * 8 + (ln >> 3);          // staging row within 64-row part
  const int scol = ((ln & 7) ^ (ln >> 3)) * 8; // pre-swizzled source col (elem)

  const u16* Abase = A + (size_t)mb * 2048;
  const u16* Bbase = Bt + (size_t)nb * 2048;

  f32x4 acc[8][3] = {};

#define STAGE_S1(kt_, buf_)                                                                        \
  do {                                                                                             \
    const u16* as_ = Abase + (size_t)srow * 2048 + (kt_) * 64 + scol;                              \
    const u16* bs_ = Bbase + (size_t)srow * 2048 + (kt_) * 64 + scol;                              \
    __builtin_amdgcn_global_load_lds(                                                              \
        (const __attribute__((address_space(1))) void*)(as_),                                      \
        (__attribute__((address_space(3))) void*)(&As[buf_][0 * 4096 + w * 512]), 16, 0, 0);       \
    __builtin_amdgcn_global_load_lds(                                                              \
        (const __attribute__((address_space(1))) void*)(as_ + (size_t)2 * 64 * 2048),              \
        (__attribute__((address_space(3))) void*)(&As[buf_][2 * 4096 + w * 512]), 16, 0, 0);       \
    _Pragma("unroll")                                                                              \
    for (int p = 0; p < 3; ++p)                                                                    \
      __builtin_amdgcn_global_load_lds(                                                            \
          (const __attribute__((address_space(1))) void*)(bs_ + (size_t)p * 64 * 2048),            \
          (__attribute__((address_space(3))) void*)(&Bs[buf_][p * 4096 + w * 512]), 16, 0, 0);     \
  } while (0)

#define STAGE_S2(kt_, buf_)                                                                        \
  do {                                                                                             \
    const u16* as_ = Abase + (size_t)srow * 2048 + (kt_) * 64 + scol;                              \
    __builtin_amdgcn_global_load_lds(                                                              \
        (const __attribute__((address_space(1))) void*)(as_ + (size_t)1 * 64 * 2048),              \
        (__attribute__((address_space(3))) void*)(&As[buf_][1 * 4096 + w * 512]), 16, 0, 0);       \
    __builtin_amdgcn_global_load_lds(                                                              \
        (const __attribute__((address_space(1))) void*)(as_ + (size_t)3 * 64 * 2048),              \
        (__attribute__((address_space(3))) void*)(&As[buf_][3 * 4096 + w * 512]), 16, 0, 0);       \
  } while (0)

  STAGE_S1(0, 0);
  STAGE_S2(0, 0);
  asm volatile("s_waitcnt vmcnt(0)" ::: "memory");
  __builtin_amdgcn_s_barrier();

  for (int kt = 0; kt < 32; ++kt) {
    const int cur = kt & 1;
    const int ktn = (kt + 1) & 31;   // last iter: dummy re-stage of tile 0 (never read)
    const u16* At = &As[cur][0];
    const u16* Bl = &Bs[cur][0];
    short8 af[4][2], bf[3][2];

    // ---- P1: wait S1(kt) (S2(kt) stays in flight); read A-lo + B; issue S1(kt+1); MFMA lo ----
    asm volatile("s_waitcnt vmcnt(2)" ::: "memory");
    __builtin_amdgcn_s_barrier();
#pragma unroll
    for (int mi = 0; mi < 4; ++mi)
#pragma unroll
      for (int ks = 0; ks < 2; ++ks)
        af[mi][ks] = *(const short8*)(At + (wm * 128 + mi * 16 + lr) * 64 + ((ks * 32 + lg * 8) ^ cswz));
#pragma unroll
    for (int ni = 0; ni < 3; ++ni)
#pragma unroll
      for (int ks = 0; ks < 2; ++ks)
        bf[ni][ks] = *(const short8*)(Bl + (wn * 48 + ni * 16 + lr) * 64 + ((ks * 32 + lg * 8) ^ cswz));
    STAGE_S1(ktn, cur ^ 1);
    __builtin_amdgcn_s_barrier();
    __builtin_amdgcn_s_setprio(1);
#pragma unroll
    for (int mi = 0; mi < 4; ++mi)
#pragma unroll
      for (int ni = 0; ni < 3; ++ni)
#pragma unroll
        for (int ks = 0; ks < 2; ++ks)
          acc[mi][ni] = __builtin_amdgcn_mfma_f32_16x16x32_bf16(af[mi][ks], bf[ni][ks], acc[mi][ni], 0, 0, 0);
    __builtin_amdgcn_s_setprio(0);

    // ---- P2: wait S2(kt) (S1(kt+1) stays in flight); read A-hi; issue S2(kt+1); MFMA hi ----
    asm volatile("s_waitcnt vmcnt(5)" ::: "memory");
    __builtin_amdgcn_s_barrier();
#pragma unroll
    for (int mi = 0; mi < 4; ++mi)
#pragma unroll
      for (int ks = 0; ks < 2; ++ks)
        af[mi][ks] = *(const short8*)(At + (wm * 128 + 64 + mi * 16 + lr) * 64 + ((ks * 32 + lg * 8) ^ cswz));
    STAGE_S2(ktn, cur ^ 1);
    __builtin_amdgcn_s_barrier();
    __builtin_amdgcn_s_setprio(1);
#pragma unroll
    for (int mi = 0; mi < 4; ++mi)
#pragma unroll
      for (int ni = 0; ni < 3; ++ni)
#pragma unroll
        for (int ks = 0; ks < 2; ++ks)
          acc[4 + mi][ni] = __builtin_amdgcn_mfma_f32_16x16x32_bf16(af[mi][ks], bf[ni][ks], acc[4 + mi][ni], 0, 0, 0);
    __builtin_amdgcn_s_setprio(0);
  }
#undef STAGE_S1
#undef STAGE_S2
  asm volatile("s_waitcnt vmcnt(0)" ::: "memory");  // drain dummy stage before epilogue

  // epilogue: bias + per-ni q/k/v routing (16-col lane groups are 16-aligned; 2048 % 16 == 0
  // so a group never straddles the q/k/v boundary -> dst uniform per group)
#pragma unroll
  for (int ni = 0; ni < 3; ++ni) {
    int ncol = nb + wn * 48 + ni * 16 + lr;
    u16* dst = (ncol < 2048) ? qb : (ncol < 4096 ? kbuf : vbuf);
    int nmod = ncol & 2047;
    float bv = bias[ncol];
#pragma unroll
    for (int m = 0; m < 8; ++m) {
#pragma unroll
      for (int r = 0; r < 4; ++r) {
        int mrow = mb + wm * 128 + m * 16 + lg * 4 + r;
        dst[(size_t)mrow * 2048 + nmod] = f2b(acc[m][ni][r] + bv);
      }
    }
  }
}

// ---------------- V transpose + column partial sums ----------------
__global__ __launch_bounds__(256) void k_vtrans(const u16* __restrict__ v, u16* __restrict__ vt,
                                                float* __restrict__ part) {
  __shared__ u16 L[128 * 136];
  __shared__ float Ls2[256];
  const int t = threadIdx.x;
  const int bh = blockIdx.y, sc = blockIdx.x;  // sc: 128-row s-chunk, 0..15
  const size_t base = (size_t)bh * 262144;
#pragma unroll
  for (int it = 0; it < 8; ++it) {
    int chunk = it * 256 + t;
    int s = chunk >> 4, d8 = (chunk & 15) * 8;
    *(short8*)(L + s * 136 + d8) = *(const short8*)(v + base + (size_t)(sc * 128 + s) * 128 + d8);
  }
  __syncthreads();
#pragma unroll
  for (int it = 0; it < 8; ++it) {
    int chunk = it * 256 + t;
    int dh = chunk >> 4, s8 = (chunk & 15) * 8;
    short8 o;
#pragma unroll
    for (int e = 0; e < 8; ++e) o[e] = (short)L[(s8 + e) * 136 + dh];
    *(short8*)(vt + base + (size_t)dh * 2048 + sc * 128 + s8) = o;
  }
  {
    const int dh = t & 127, seg = t >> 7;
    float ps = 0.f;
#pragma unroll 8
    for (int i = 0; i < 64; ++i) ps += b2f(L[(seg * 64 + i) * 136 + dh]);
    Ls2[t] = ps;
    __syncthreads();
    if (t < 128) part[((size_t)bh * 16 + sc) * 128 + t] = Ls2[t] + Ls2[t + 128];
  }
}

// ---------------- flash attention: T2-swizzled unpadded LDS, 4 blocks/CU ----------------
// R15: Ks[64][128], Vs[128][64], Ps[16][64] all XOR-swizzled (col8' = col8 ^ (row&7),
// same involution on write and read -> bank-group 2-way = free; was 8-way with padding).
// LDS 40960 B exactly -> 4 blocks/CU (was 3).  Staging is reg-based so both sides swizzle
// freely (rule #21).  Everything else unchanged from R9 (1024 blocks, long strips first,
// XCD swizzle, NO-MAX softmax, lane-local row-sums, analytic row 0).
__global__ __launch_bounds__(256, 4) void k_attn(const u16* __restrict__ qb,
                                                 const u16* __restrict__ kb,
                                                 const u16* __restrict__ vt,
                                                 const float* __restrict__ part,
                                                 float* __restrict__ out) {
  __shared__ u16 Ks[64 * 128];   // [sk][d], swizzled, no pad
  __shared__ u16 Vs[128 * 64];   // V^T [dh][sk], swizzled, no pad
  __shared__ u16 Ps[4][16 * 64]; // per-wave P [qrow][sk], swizzled, no pad
  const int t = threadIdx.x;
  const int ln = t & 63, wv = t >> 6;
  const int lr = ln & 15, lg = ln >> 4;
  const int lr7 = lr & 7;
  const int L = blockIdx.y * 32 + blockIdx.x;      // launched linear id (x fastest), 0..1023
  const int wl = (L & 7) * 128 + (L >> 3);         // bijective XCD-aware remap (1024 blocks)
  const int bh = wl >> 5;                          // 4 heads per XCD chunk of 128 blocks
  const int qt = 31 - (wl & 31);                   // long strips first in dispatch order
  const size_t base = (size_t)bh * 262144;  // contiguous [2048][128] per head
  const u16* Qh = qb + base;
  const u16* Kh = kb + base;
  const u16* Vth = vt + base;
  float* Oh = out + base;
  const int qs = qt * 64;

  short8 qf[4];
  {
    int qr = qs + wv * 16 + lr;
#pragma unroll
    for (int ks = 0; ks < 4; ++ks)
      qf[ks] = *(const short8*)(Qh + (size_t)qr * 128 + ks * 32 + lg * 8);
  }
  float lsum[4] = {0.f, 0.f, 0.f, 0.f};  // lane-local partial row-sums
  f32x4 acc[8];
  const f32x4 fz = {0.f, 0.f, 0.f, 0.f};
#pragma unroll
  for (int oj = 0; oj < 8; ++oj) acc[oj] = fz;

  u16* Pw = &Ps[wv][0];
  const int nkt = qt + 1;
  for (int kt = 0; kt < nkt; ++kt) {
    // stage K [64][128] and V^T [128][64], swizzled writes (col8' = col8 ^ (row&7))
#pragma unroll
    for (int it = 0; it < 4; ++it) {
      int chunk = it * 256 + t;
      int sk = chunk >> 4, c8 = chunk & 15;
      *(short8*)(Ks + sk * 128 + (c8 ^ (sk & 7)) * 8) =
          *(const short8*)(Kh + (size_t)(kt * 64 + sk) * 128 + c8 * 8);
    }
#pragma unroll
    for (int it = 0; it < 4; ++it) {
      int chunk = it * 256 + t;
      int dh = chunk >> 3, c8 = chunk & 7;
      *(short8*)(Vs + dh * 64 + (c8 ^ (dh & 7)) * 8) =
          *(const short8*)(Vth + (size_t)dh * 2048 + kt * 64 + c8 * 8);
    }
    __syncthreads();

    f32x4 s[4];
#pragma unroll
    for (int ni = 0; ni < 4; ++ni) s[ni] = fz;
#pragma unroll
    for (int ks = 0; ks < 4; ++ks) {
#pragma unroll
      for (int ni = 0; ni < 4; ++ni) {
        short8 kf = *(const short8*)(Ks + (ni * 16 + lr) * 128 + ((ks * 4 + lg) ^ lr7) * 8);
        s[ni] = __builtin_amdgcn_mfma_f32_16x16x32_bf16(qf[ks], kf, s[ni], 0, 0, 0);
      }
    }
    if (kt == qt) {  // diagonal tile: mask col >= row (diagonal included)
#pragma unroll
      for (int ni = 0; ni < 4; ++ni) {
        int col = kt * 64 + ni * 16 + lr;
#pragma unroll
        for (int r = 0; r < 4; ++r) {
          int row = qs + wv * 16 + lg * 4 + r;
          if (col >= row) s[ni][r] = NEGR;
        }
      }
    }
#pragma unroll
    for (int ni = 0; ni < 4; ++ni)
#pragma unroll
      for (int r = 0; r < 4; ++r) {
        u16 h = f2b(exp2f(s[ni][r] * CSL));
        int pr = lg * 4 + r, pc = ni * 16 + lr;
        Pw[pr * 64 + ((pc >> 3) ^ (pr & 7)) * 8 + (pc & 7)] = h;
        lsum[r] += b2f(h);   // denominator from the same rounded weights PV uses
      }
#pragma unroll
    for (int ks2 = 0; ks2 < 2; ++ks2) {
      short8 pa = *(const short8*)(Pw + lr * 64 + ((ks2 * 4 + lg) ^ lr7) * 8);
#pragma unroll
      for (int oj = 0; oj < 8; ++oj) {
        short8 vf = *(const short8*)(Vs + (oj * 16 + lr) * 64 + ((ks2 * 4 + lg) ^ lr7) * 8);
        acc[oj] = __builtin_amdgcn_mfma_f32_16x16x32_bf16(pa, vf, acc[oj], 0, 0, 0);
      }
    }
    __syncthreads();
  }

  // epilogue: single cross-lane reduction of the row-sums, then divide.
  float rl[4];
#pragma unroll
  for (int r = 0; r < 4; ++r) {
    float sa = lsum[r];
#pragma unroll
    for (int d = 1; d < 16; d <<= 1) sa += __shfl_xor(sa, d, 64);
    rl[r] = 1.0f / sa;  // row 0 gives inf; overwritten analytically below
  }
#pragma unroll
  for (int oj = 0; oj < 8; ++oj)
#pragma unroll
    for (int r = 0; r < 4; ++r) {
      int row = qs + wv * 16 + lg * 4 + r;
      float val = acc[oj][r] * rl[r];
      if (qt == 0 && wv == 0 && lg == 0 && r == 0) {
        float vs = 0.f;
#pragma unroll
        for (int sc = 0; sc < 16; ++sc) vs += part[(size_t)bh * 2048 + sc * 128 + oj * 16 + lr];
        val = vs * (1.0f / 2048.0f);
      }
      Oh[(size_t)row * 128 + oj * 16 + lr] = val;
    }
}

extern "C" void kernel_launch(void* const* d_in, const int* in_sizes, int n_in,
                              void* d_out, int out_size, void* d_ws, size_t ws_size,
                              hipStream_t stream) {
  (void)in_sizes; (void)n_in; (void)out_size; (void)ws_size;
  const float* q_in = (const float*)d_in[0];
  const float* W = (const float*)d_in[3];
  const float* bias = (const float*)d_in[4];
  float* out = (float*)d_out;

  // workspace layout (bf16 elements unless noted); total ~109.3 MB
  u16* qbf = (u16*)d_ws;                      // 4096*2048
  u16* wtb = qbf + (size_t)4096 * 2048;       // 6144*2048
  u16* qb  = wtb + (size_t)6144 * 2048;       // 4096*2048
  u16* kbf = qb  + (size_t)4096 * 2048;       // 4096*2048
  u16* vbf = kbf + (size_t)4096 * 2048;       // 4096*2048
  u16* vt  = vbf + (size_t)4096 * 2048;       // 4096*2048
  float* part = (float*)(vt + (size_t)4096 * 2048);  // [32][16][128] f32 col-chunk sums

  k_cast_q<<<4096, 256, 0, stream>>>(q_in, qbf);
  k_cast_wt<<<dim3(96, 32), 256, 0, stream>>>(W, wtb);
  k_gemm256<<<512, 512, 0, stream>>>(qbf, wtb, bias, qb, kbf, vbf);
  k_vtrans<<<dim3(16, 32), 256, 0, stream>>>(vbf, vt, part);
  k_attn<<<dim3(32, 32), 256, 0, stream>>>(qb, kbf, vt, part, out);
}

// Round 16
// 225.450 us; speedup vs baseline: 1.2136x; 1.2136x over previous
//
#include <hip/hip_runtime.h>
#include <hip/hip_bf16.h>
#include <stdint.h>

typedef unsigned short u16;
typedef short short8 __attribute__((ext_vector_type(8)));
typedef short short4v __attribute__((ext_vector_type(4)));
typedef float f32x4 __attribute__((ext_vector_type(4)));

// scale folded into exp2: (1/sqrt(128)) * log2(e)
#define CSL (0.08838834764831845f * 1.4426950408889634f)
#define NEGR -1.0e13f   // raw-score mask value; *CSL -> -1.27e12 -> exp2 -> exactly 0

// B=2, S=2048, D=2048, H=16, DH=128.  M = B*S = 4096, N3 = 3*D = 6144, K = 2048.

__device__ __forceinline__ u16 f2b(float f) {
  union { float f; unsigned int u; } c; c.f = f;
  unsigned int u = c.u;
  u += 0x7fffu + ((u >> 16) & 1u);   // RNE; inputs are finite
  return (u16)(u >> 16);
}
__device__ __forceinline__ float b2f(u16 h) {
  union { float f; unsigned int u; } c; c.u = ((unsigned int)h) << 16;
  return c.f;
}

// ---------------- fused input casts: query f32->bf16 (blocks 0..4095) and
// W [2048][6144] f32 -> Wt [6144][2048] bf16 transpose-cast (blocks 4096..7167) ----------------
__global__ __launch_bounds__(256) void k_cast_fused(const float* __restrict__ q_in,
                                                    u16* __restrict__ qbf,
                                                    const float* __restrict__ W,
                                                    u16* __restrict__ Wt) {
  __shared__ u16 L[64 * 68];
  const int t = threadIdx.x;
  const int b = blockIdx.x;
  if (b < 4096) {
    size_t idx = ((size_t)b * 256 + t) * 8;
    float4 f0 = *(const float4*)(q_in + idx);
    float4 f1 = *(const float4*)(q_in + idx + 4);
    short8 o;
    o[0] = (short)f2b(f0.x); o[1] = (short)f2b(f0.y); o[2] = (short)f2b(f0.z); o[3] = (short)f2b(f0.w);
    o[4] = (short)f2b(f1.x); o[5] = (short)f2b(f1.y); o[6] = (short)f2b(f1.z); o[7] = (short)f2b(f1.w);
    *(short8*)(qbf + idx) = o;
    return;
  }
  const int wb = b - 4096;                 // 0..3071
  const int nb = (wb % 96) * 64;           // n base (0..6143)
  const int kb = (wb / 96) * 64;           // k base (0..2047)
#pragma unroll
  for (int it = 0; it < 4; ++it) {
    int idx = it * 1024 + t * 4;
    int r = idx >> 6, c = idx & 63;
    float4 f = *(const float4*)(W + (size_t)(kb + r) * 6144 + nb + c);
    L[r * 68 + c + 0] = f2b(f.x);
    L[r * 68 + c + 1] = f2b(f.y);
    L[r * 68 + c + 2] = f2b(f.z);
    L[r * 68 + c + 3] = f2b(f.w);
  }
  __syncthreads();
#pragma unroll
  for (int it = 0; it < 4; ++it) {
    int idx = it * 1024 + t * 4;
    int i = idx >> 6, j = idx & 63;
    short4v o;
#pragma unroll
    for (int e = 0; e < 4; ++e) o[e] = (short)L[(j + e) * 68 + i];
    *(short4v*)(Wt + (size_t)(nb + i) * 2048 + kb + j) = o;
  }
}

// ---------------- QKV GEMM, 256x192, counted-vmcnt pipeline (exact R12: measured best 124 us) ----------------
// 512 thr = 8 waves (2M x 4N -> wave tile 128x48), BK=64, LDS 112 KiB dbuf, 512 blocks = 2 rounds.
// Supertile XCD map + T2 swizzle (verified: FETCH ~90 MB, conflicts 0).
// T4: S1={A p0,p2 + B p0-2} (5 loads -> P1), S2={A p1,p3} (2 loads -> P2).
// vmcnt(2) before P1 (drain S1(kt), keep S2(kt)); vmcnt(5) before P2 (drain S2(kt), keep S1(kt+1)).
__global__ __launch_bounds__(512, 1) void k_gemm256(const u16* __restrict__ A,
                                                    const u16* __restrict__ Bt,
                                                    const float* __restrict__ bias,
                                                    u16* __restrict__ qb,
                                                    u16* __restrict__ kbuf,
                                                    u16* __restrict__ vbuf) {
  __shared__ u16 As[2][16384];   // [dbuf][256 rows x 64 el], swizzled
  __shared__ u16 Bs[2][12288];   // [dbuf][192 rows x 64 el], swizzled
  const int t = threadIdx.x;
  const int ln = t & 63, w = t >> 6;
  const int lr = ln & 15, lg = ln >> 4;
  const int wm = w >> 2, wn = w & 3;           // 2 x 4 wave grid
  const int Lid = blockIdx.x;                  // 0..511
  const int xcd = Lid & 7, l = Lid >> 3;       // 64 blocks per XCD
  const int mt = (xcd & 1) * 8 + (l & 7);      // supertile: 8m x 8n, m-fastest
  const int nt = (xcd >> 1) * 8 + (l >> 3);
  const int mb = mt * 256, nb = nt * 192;
  const int cswz = (lr & 7) * 8;               // read-side swizzle (elem)
  const int srow = w * 8 + (ln >> 3);          // staging row within 64-row part
  const int scol = ((ln & 7) ^ (ln >> 3)) * 8; // pre-swizzled source col (elem)

  const u16* Abase = A + (size_t)mb * 2048;
  const u16* Bbase = Bt + (size_t)nb * 2048;

  f32x4 acc[8][3] = {};

#define STAGE_S1(kt_, buf_)                                                                        \
  do {                                                                                             \
    const u16* as_ = Abase + (size_t)srow * 2048 + (kt_) * 64 + scol;                              \
    const u16* bs_ = Bbase + (size_t)srow * 2048 + (kt_) * 64 + scol;                              \
    __builtin_amdgcn_global_load_lds(                                                              \
        (const __attribute__((address_space(1))) void*)(as_),                                      \
        (__attribute__((address_space(3))) void*)(&As[buf_][0 * 4096 + w * 512]), 16, 0, 0);       \
    __builtin_amdgcn_global_load_lds(                                                              \
        (const __attribute__((address_space(1))) void*)(as_ + (size_t)2 * 64 * 2048),              \
        (__attribute__((address_space(3))) void*)(&As[buf_][2 * 4096 + w * 512]), 16, 0, 0);       \
    _Pragma("unroll")                                                                              \
    for (int p = 0; p < 3; ++p)                                                                    \
      __builtin_amdgcn_global_load_lds(                                                            \
          (const __attribute__((address_space(1))) void*)(bs_ + (size_t)p * 64 * 2048),            \
          (__attribute__((address_space(3))) void*)(&Bs[buf_][p * 4096 + w * 512]), 16, 0, 0);     \
  } while (0)

#define STAGE_S2(kt_, buf_)                                                                        \
  do {                                                                                             \
    const u16* as_ = Abase + (size_t)srow * 2048 + (kt_) * 64 + scol;                              \
    __builtin_amdgcn_global_load_lds(                                                              \
        (const __attribute__((address_space(1))) void*)(as_ + (size_t)1 * 64 * 2048),              \
        (__attribute__((address_space(3))) void*)(&As[buf_][1 * 4096 + w * 512]), 16, 0, 0);       \
    __builtin_amdgcn_global_load_lds(                                                              \
        (const __attribute__((address_space(1))) void*)(as_ + (size_t)3 * 64 * 2048),              \
        (__attribute__((address_space(3))) void*)(&As[buf_][3 * 4096 + w * 512]), 16, 0, 0);       \
  } while (0)

  STAGE_S1(0, 0);
  STAGE_S2(0, 0);
  asm volatile("s_waitcnt vmcnt(0)" ::: "memory");
  __builtin_amdgcn_s_barrier();

  for (int kt = 0; kt < 32; ++kt) {
    const int cur = kt & 1;
    const int ktn = (kt + 1) & 31;   // last iter: dummy re-stage of tile 0 (never read)
    const u16* At = &As[cur][0];
    const u16* Bl = &Bs[cur][0];
    short8 af[4][2], bf[3][2];

    // ---- P1: wait S1(kt) (S2(kt) stays in flight); read A-lo + B; issue S1(kt+1); MFMA lo ----
    asm volatile("s_waitcnt vmcnt(2)" ::: "memory");
    __builtin_amdgcn_s_barrier();
#pragma unroll
    for (int mi = 0; mi < 4; ++mi)
#pragma unroll
      for (int ks = 0; ks < 2; ++ks)
        af[mi][ks] = *(const short8*)(At + (wm * 128 + mi * 16 + lr) * 64 + ((ks * 32 + lg * 8) ^ cswz));
#pragma unroll
    for (int ni = 0; ni < 3; ++ni)
#pragma unroll
      for (int ks = 0; ks < 2; ++ks)
        bf[ni][ks] = *(const short8*)(Bl + (wn * 48 + ni * 16 + lr) * 64 + ((ks * 32 + lg * 8) ^ cswz));
    STAGE_S1(ktn, cur ^ 1);
    __builtin_amdgcn_s_barrier();
    __builtin_amdgcn_s_setprio(1);
#pragma unroll
    for (int mi = 0; mi < 4; ++mi)
#pragma unroll
      for (int ni = 0; ni < 3; ++ni)
#pragma unroll
        for (int ks = 0; ks < 2; ++ks)
          acc[mi][ni] = __builtin_amdgcn_mfma_f32_16x16x32_bf16(af[mi][ks], bf[ni][ks], acc[mi][ni], 0, 0, 0);
    __builtin_amdgcn_s_setprio(0);

    // ---- P2: wait S2(kt) (S1(kt+1) stays in flight); read A-hi; issue S2(kt+1); MFMA hi ----
    asm volatile("s_waitcnt vmcnt(5)" ::: "memory");
    __builtin_amdgcn_s_barrier();
#pragma unroll
    for (int mi = 0; mi < 4; ++mi)
#pragma unroll
      for (int ks = 0; ks < 2; ++ks)
        af[mi][ks] = *(const short8*)(At + (wm * 128 + 64 + mi * 16 + lr) * 64 + ((ks * 32 + lg * 8) ^ cswz));
    STAGE_S2(ktn, cur ^ 1);
    __builtin_amdgcn_s_barrier();
    __builtin_amdgcn_s_setprio(1);
#pragma unroll
    for (int mi = 0; mi < 4; ++mi)
#pragma unroll
      for (int ni = 0; ni < 3; ++ni)
#pragma unroll
        for (int ks = 0; ks < 2; ++ks)
          acc[4 + mi][ni] = __builtin_amdgcn_mfma_f32_16x16x32_bf16(af[mi][ks], bf[ni][ks], acc[4 + mi][ni], 0, 0, 0);
    __builtin_amdgcn_s_setprio(0);
  }
#undef STAGE_S1
#undef STAGE_S2
  asm volatile("s_waitcnt vmcnt(0)" ::: "memory");  // drain dummy stage before epilogue

  // epilogue: bias + per-ni q/k/v routing (16-col lane groups are 16-aligned; 2048 % 16 == 0
  // so a group never straddles the q/k/v boundary -> dst uniform per group)
#pragma unroll
  for (int ni = 0; ni < 3; ++ni) {
    int ncol = nb + wn * 48 + ni * 16 + lr;
    u16* dst = (ncol < 2048) ? qb : (ncol < 4096 ? kbuf : vbuf);
    int nmod = ncol & 2047;
    float bv = bias[ncol];
#pragma unroll
    for (int m = 0; m < 8; ++m) {
#pragma unroll
      for (int r = 0; r < 4; ++r) {
        int mrow = mb + wm * 128 + m * 16 + lg * 4 + r;
        dst[(size_t)mrow * 2048 + nmod] = f2b(acc[m][ni][r] + bv);
      }
    }
  }
}

// ---------------- V transpose + column partial sums ----------------
__global__ __launch_bounds__(256) void k_vtrans(const u16* __restrict__ v, u16* __restrict__ vt,
                                                float* __restrict__ part) {
  __shared__ u16 L[128 * 136];
  __shared__ float Ls2[256];
  const int t = threadIdx.x;
  const int bh = blockIdx.y, sc = blockIdx.x;  // sc: 128-row s-chunk, 0..15
  const size_t base = (size_t)bh * 262144;
#pragma unroll
  for (int it = 0; it < 8; ++it) {
    int chunk = it * 256 + t;
    int s = chunk >> 4, d8 = (chunk & 15) * 8;
    *(short8*)(L + s * 136 + d8) = *(const short8*)(v + base + (size_t)(sc * 128 + s) * 128 + d8);
  }
  __syncthreads();
#pragma unroll
  for (int it = 0; it < 8; ++it) {
    int chunk = it * 256 + t;
    int dh = chunk >> 4, s8 = (chunk & 15) * 8;
    short8 o;
#pragma unroll
    for (int e = 0; e < 8; ++e) o[e] = (short)L[(s8 + e) * 136 + dh];
    *(short8*)(vt + base + (size_t)dh * 2048 + sc * 128 + s8) = o;
  }
  {
    const int dh = t & 127, seg = t >> 7;
    float ps = 0.f;
#pragma unroll 8
    for (int i = 0; i < 64; ++i) ps += b2f(L[(seg * 64 + i) * 136 + dh]);
    Ls2[t] = ps;
    __syncthreads();
    if (t < 128) part[((size_t)bh * 16 + sc) * 128 + t] = Ls2[t] + Ls2[t + 128];
  }
}

// ---------------- flash attention, single q-strip per block, NO-MAX softmax ----------------
// (exact R9/R12 version — measured ~73 us; padded LDS is at the b128 throughput floor,
// the 9.2M conflict counter is scalar-u16 P-write dword pairing, near-irreducible here)
__global__ __launch_bounds__(256, 3) void k_attn(const u16* __restrict__ qb,
                                                 const u16* __restrict__ kb,
                                                 const u16* __restrict__ vt,
                                                 const float* __restrict__ part,
                                                 float* __restrict__ out) {
  __shared__ u16 Ks[64 * 136];   // [sk][dh], padded
  __shared__ u16 Vs[128 * 72];   // V^T tile [dh][sk], padded
  __shared__ u16 Ps[4][16 * 72]; // per-wave P tile [qrow][sk], padded
  const int t = threadIdx.x;
  const int ln = t & 63, wv = t >> 6;
  const int lr = ln & 15, lg = ln >> 4;
  const int L = blockIdx.y * 32 + blockIdx.x;      // launched linear id (x fastest), 0..1023
  const int wl = (L & 7) * 128 + (L >> 3);         // bijective XCD-aware remap (1024 blocks)
  const int bh = wl >> 5;                          // 4 heads per XCD chunk of 128 blocks
  const int qt = 31 - (wl & 31);                   // long strips first in dispatch order
  const size_t base = (size_t)bh * 262144;  // contiguous [2048][128] per head
  const u16* Qh = qb + base;
  const u16* Kh = kb + base;
  const u16* Vth = vt + base;
  float* Oh = out + base;
  const int qs = qt * 64;

  short8 qf[4];
  {
    int qr = qs + wv * 16 + lr;
#pragma unroll
    for (int ks = 0; ks < 4; ++ks)
      qf[ks] = *(const short8*)(Qh + (size_t)qr * 128 + ks * 32 + lg * 8);
  }
  float lsum[4] = {0.f, 0.f, 0.f, 0.f};  // lane-local partial row-sums
  f32x4 acc[8];
  const f32x4 fz = {0.f, 0.f, 0.f, 0.f};
#pragma unroll
  for (int oj = 0; oj < 8; ++oj) acc[oj] = fz;

  u16* Pw = &Ps[wv][0];
  const int nkt = qt + 1;
  for (int kt = 0; kt < nkt; ++kt) {
    // stage K [64][128] and V^T [128][64]
#pragma unroll
    for (int it = 0; it < 4; ++it) {
      int chunk = it * 256 + t;
      int sk = chunk >> 4, d8 = (chunk & 15) * 8;
      *(short8*)(Ks + sk * 136 + d8) = *(const short8*)(Kh + (size_t)(kt * 64 + sk) * 128 + d8);
    }
#pragma unroll
    for (int it = 0; it < 4; ++it) {
      int chunk = it * 256 + t;
      int dh = chunk >> 3, s8 = (chunk & 7) * 8;
      *(short8*)(Vs + dh * 72 + s8) = *(const short8*)(Vth + (size_t)dh * 2048 + kt * 64 + s8);
    }
    __syncthreads();

    f32x4 s[4];
#pragma unroll
    for (int ni = 0; ni < 4; ++ni) s[ni] = fz;
#pragma unroll
    for (int ks = 0; ks < 4; ++ks) {
#pragma unroll
      for (int ni = 0; ni < 4; ++ni) {
        short8 kf = *(const short8*)(Ks + (ni * 16 + lr) * 136 + ks * 32 + lg * 8);
        s[ni] = __builtin_amdgcn_mfma_f32_16x16x32_bf16(qf[ks], kf, s[ni], 0, 0, 0);
      }
    }
    if (kt == qt) {  // diagonal tile: mask col >= row (diagonal included)
#pragma unroll
      for (int ni = 0; ni < 4; ++ni) {
        int col = kt * 64 + ni * 16 + lr;
#pragma unroll
        for (int r = 0; r < 4; ++r) {
          int row = qs + wv * 16 + lg * 4 + r;
          if (col >= row) s[ni][r] = NEGR;
        }
      }
    }
#pragma unroll
    for (int ni = 0; ni < 4; ++ni)
#pragma unroll
      for (int r = 0; r < 4; ++r) {
        u16 h = f2b(exp2f(s[ni][r] * CSL));
        Pw[(lg * 4 + r) * 72 + ni * 16 + lr] = h;
        lsum[r] += b2f(h);   // denominator from the same rounded weights PV uses
      }
#pragma unroll
    for (int ks2 = 0; ks2 < 2; ++ks2) {
      short8 pa = *(const short8*)(Pw + lr * 72 + ks2 * 32 + lg * 8);
#pragma unroll
      for (int oj = 0; oj < 8; ++oj) {
        short8 vf = *(const short8*)(Vs + (oj * 16 + lr) * 72 + ks2 * 32 + lg * 8);
        acc[oj] = __builtin_amdgcn_mfma_f32_16x16x32_bf16(pa, vf, acc[oj], 0, 0, 0);
      }
    }
    __syncthreads();
  }

  // epilogue: single cross-lane reduction of the row-sums, then divide.
  float rl[4];
#pragma unroll
  for (int r = 0; r < 4; ++r) {
    float sa = lsum[r];
#pragma unroll
    for (int d = 1; d < 16; d <<= 1) sa += __shfl_xor(sa, d, 64);
    rl[r] = 1.0f / sa;  // row 0 gives inf; overwritten analytically below
  }
#pragma unroll
  for (int oj = 0; oj < 8; ++oj)
#pragma unroll
    for (int r = 0; r < 4; ++r) {
      int row = qs + wv * 16 + lg * 4 + r;
      float val = acc[oj][r] * rl[r];
      if (qt == 0 && wv == 0 && lg == 0 && r == 0) {
        float vs = 0.f;
#pragma unroll
        for (int sc = 0; sc < 16; ++sc) vs += part[(size_t)bh * 2048 + sc * 128 + oj * 16 + lr];
        val = vs * (1.0f / 2048.0f);
      }
      Oh[(size_t)row * 128 + oj * 16 + lr] = val;
    }
}

extern "C" void kernel_launch(void* const* d_in, const int* in_sizes, int n_in,
                              void* d_out, int out_size, void* d_ws, size_t ws_size,
                              hipStream_t stream) {
  (void)in_sizes; (void)n_in; (void)out_size; (void)ws_size;
  const float* q_in = (const float*)d_in[0];
  const float* W = (const float*)d_in[3];
  const float* bias = (const float*)d_in[4];
  float* out = (float*)d_out;

  // workspace layout (bf16 elements unless noted); total ~109.3 MB
  u16* qbf = (u16*)d_ws;                      // 4096*2048
  u16* wtb = qbf + (size_t)4096 * 2048;       // 6144*2048
  u16* qb  = wtb + (size_t)6144 * 2048;       // 4096*2048
  u16* kbf = qb  + (size_t)4096 * 2048;       // 4096*2048
  u16* vbf = kbf + (size_t)4096 * 2048;       // 4096*2048
  u16* vt  = vbf + (size_t)4096 * 2048;       // 4096*2048
  float* part = (float*)(vt + (size_t)4096 * 2048);  // [32][16][128] f32 col-chunk sums

  k_cast_fused<<<7168, 256, 0, stream>>>(q_in, qbf, W, wtb);
  k_gemm256<<<512, 512, 0, stream>>>(qbf, wtb, bias, qb, kbf, vbf);
  k_vtrans<<<dim3(16, 32), 256, 0, stream>>>(vbf, vt, part);
  k_attn<<<dim3(32, 32), 256, 0, stream>>>(qb, kbf, vt, part, out);
}

// Round 17
// 219.755 us; speedup vs baseline: 1.2450x; 1.0259x over previous
//
#include <hip/hip_runtime.h>
#include <hip/hip_bf16.h>
#include <stdint.h>

typedef unsigned short u16;
typedef short short8 __attribute__((ext_vector_type(8)));
typedef short short4v __attribute__((ext_vector_type(4)));
typedef float f32x4 __attribute__((ext_vector_type(4)));

// scale folded into exp2: (1/sqrt(128)) * log2(e)
#define CSL (0.08838834764831845f * 1.4426950408889634f)
#define NEGR -1.0e13f   // raw-score mask value; *CSL -> -1.27e12 -> exp2 -> exactly 0

// B=2, S=2048, D=2048, H=16, DH=128.  M = B*S = 4096, N3 = 3*D = 6144, K = 2048.

__device__ __forceinline__ u16 f2b(float f) {
  union { float f; unsigned int u; } c; c.f = f;
  unsigned int u = c.u;
  u += 0x7fffu + ((u >> 16) & 1u);   // RNE; inputs are finite
  return (u16)(u >> 16);
}
__device__ __forceinline__ float b2f(u16 h) {
  union { float f; unsigned int u; } c; c.u = ((unsigned int)h) << 16;
  return c.f;
}

// ---------------- fused input casts: query f32->bf16 (blocks 0..4095) and
// W [2048][6144] f32 -> Wt [6144][2048] bf16 transpose-cast (blocks 4096..7167) ----------------
__global__ __launch_bounds__(256) void k_cast_fused(const float* __restrict__ q_in,
                                                    u16* __restrict__ qbf,
                                                    const float* __restrict__ W,
                                                    u16* __restrict__ Wt) {
  __shared__ u16 L[64 * 68];
  const int t = threadIdx.x;
  const int b = blockIdx.x;
  if (b < 4096) {
    size_t idx = ((size_t)b * 256 + t) * 8;
    float4 f0 = *(const float4*)(q_in + idx);
    float4 f1 = *(const float4*)(q_in + idx + 4);
    short8 o;
    o[0] = (short)f2b(f0.x); o[1] = (short)f2b(f0.y); o[2] = (short)f2b(f0.z); o[3] = (short)f2b(f0.w);
    o[4] = (short)f2b(f1.x); o[5] = (short)f2b(f1.y); o[6] = (short)f2b(f1.z); o[7] = (short)f2b(f1.w);
    *(short8*)(qbf + idx) = o;
    return;
  }
  const int wb = b - 4096;                 // 0..3071
  const int nb = (wb % 96) * 64;           // n base (0..6143)
  const int kb = (wb / 96) * 64;           // k base (0..2047)
#pragma unroll
  for (int it = 0; it < 4; ++it) {
    int idx = it * 1024 + t * 4;
    int r = idx >> 6, c = idx & 63;
    float4 f = *(const float4*)(W + (size_t)(kb + r) * 6144 + nb + c);
    L[r * 68 + c + 0] = f2b(f.x);
    L[r * 68 + c + 1] = f2b(f.y);
    L[r * 68 + c + 2] = f2b(f.z);
    L[r * 68 + c + 3] = f2b(f.w);
  }
  __syncthreads();
#pragma unroll
  for (int it = 0; it < 4; ++it) {
    int idx = it * 1024 + t * 4;
    int i = idx >> 6, j = idx & 63;
    short4v o;
#pragma unroll
    for (int e = 0; e < 4; ++e) o[e] = (short)L[(j + e) * 68 + i];
    *(short4v*)(Wt + (size_t)(nb + i) * 2048 + kb + j) = o;
  }
}

// ---------------- QKV GEMM, 256x192, counted-vmcnt pipeline (exact R12: measured best 124 us) ----------------
__global__ __launch_bounds__(512, 1) void k_gemm256(const u16* __restrict__ A,
                                                    const u16* __restrict__ Bt,
                                                    const float* __restrict__ bias,
                                                    u16* __restrict__ qb,
                                                    u16* __restrict__ kbuf,
                                                    u16* __restrict__ vbuf) {
  __shared__ u16 As[2][16384];   // [dbuf][256 rows x 64 el], swizzled
  __shared__ u16 Bs[2][12288];   // [dbuf][192 rows x 64 el], swizzled
  const int t = threadIdx.x;
  const int ln = t & 63, w = t >> 6;
  const int lr = ln & 15, lg = ln >> 4;
  const int wm = w >> 2, wn = w & 3;           // 2 x 4 wave grid
  const int Lid = blockIdx.x;                  // 0..511
  const int xcd = Lid & 7, l = Lid >> 3;       // 64 blocks per XCD
  const int mt = (xcd & 1) * 8 + (l & 7);      // supertile: 8m x 8n, m-fastest
  const int nt = (xcd >> 1) * 8 + (l >> 3);
  const int mb = mt * 256, nb = nt * 192;
  const int cswz = (lr & 7) * 8;               // read-side swizzle (elem)
  const int srow = w * 8 + (ln >> 3);          // staging row within 64-row part
  const int scol = ((ln & 7) ^ (ln >> 3)) * 8; // pre-swizzled source col (elem)

  const u16* Abase = A + (size_t)mb * 2048;
  const u16* Bbase = Bt + (size_t)nb * 2048;

  f32x4 acc[8][3] = {};

#define STAGE_S1(kt_, buf_)                                                                        \
  do {                                                                                             \
    const u16* as_ = Abase + (size_t)srow * 2048 + (kt_) * 64 + scol;                              \
    const u16* bs_ = Bbase + (size_t)srow * 2048 + (kt_) * 64 + scol;                              \
    __builtin_amdgcn_global_load_lds(                                                              \
        (const __attribute__((address_space(1))) void*)(as_),                                      \
        (__attribute__((address_space(3))) void*)(&As[buf_][0 * 4096 + w * 512]), 16, 0, 0);       \
    __builtin_amdgcn_global_load_lds(                                                              \
        (const __attribute__((address_space(1))) void*)(as_ + (size_t)2 * 64 * 2048),              \
        (__attribute__((address_space(3))) void*)(&As[buf_][2 * 4096 + w * 512]), 16, 0, 0);       \
    _Pragma("unroll")                                                                              \
    for (int p = 0; p < 3; ++p)                                                                    \
      __builtin_amdgcn_global_load_lds(                                                            \
          (const __attribute__((address_space(1))) void*)(bs_ + (size_t)p * 64 * 2048),            \
          (__attribute__((address_space(3))) void*)(&Bs[buf_][p * 4096 + w * 512]), 16, 0, 0);     \
  } while (0)

#define STAGE_S2(kt_, buf_)                                                                        \
  do {                                                                                             \
    const u16* as_ = Abase + (size_t)srow * 2048 + (kt_) * 64 + scol;                              \
    __builtin_amdgcn_global_load_lds(                                                              \
        (const __attribute__((address_space(1))) void*)(as_ + (size_t)1 * 64 * 2048),              \
        (__attribute__((address_space(3))) void*)(&As[buf_][1 * 4096 + w * 512]), 16, 0, 0);       \
    __builtin_amdgcn_global_load_lds(                                                              \
        (const __attribute__((address_space(1))) void*)(as_ + (size_t)3 * 64 * 2048),              \
        (__attribute__((address_space(3))) void*)(&As[buf_][3 * 4096 + w * 512]), 16, 0, 0);       \
  } while (0)

  STAGE_S1(0, 0);
  STAGE_S2(0, 0);
  asm volatile("s_waitcnt vmcnt(0)" ::: "memory");
  __builtin_amdgcn_s_barrier();

  for (int kt = 0; kt < 32; ++kt) {
    const int cur = kt & 1;
    const int ktn = (kt + 1) & 31;   // last iter: dummy re-stage of tile 0 (never read)
    const u16* At = &As[cur][0];
    const u16* Bl = &Bs[cur][0];
    short8 af[4][2], bf[3][2];

    // ---- P1: wait S1(kt) (S2(kt) stays in flight); read A-lo + B; issue S1(kt+1); MFMA lo ----
    asm volatile("s_waitcnt vmcnt(2)" ::: "memory");
    __builtin_amdgcn_s_barrier();
#pragma unroll
    for (int mi = 0; mi < 4; ++mi)
#pragma unroll
      for (int ks = 0; ks < 2; ++ks)
        af[mi][ks] = *(const short8*)(At + (wm * 128 + mi * 16 + lr) * 64 + ((ks * 32 + lg * 8) ^ cswz));
#pragma unroll
    for (int ni = 0; ni < 3; ++ni)
#pragma unroll
      for (int ks = 0; ks < 2; ++ks)
        bf[ni][ks] = *(const short8*)(Bl + (wn * 48 + ni * 16 + lr) * 64 + ((ks * 32 + lg * 8) ^ cswz));
    STAGE_S1(ktn, cur ^ 1);
    __builtin_amdgcn_s_barrier();
    __builtin_amdgcn_s_setprio(1);
#pragma unroll
    for (int mi = 0; mi < 4; ++mi)
#pragma unroll
      for (int ni = 0; ni < 3; ++ni)
#pragma unroll
        for (int ks = 0; ks < 2; ++ks)
          acc[mi][ni] = __builtin_amdgcn_mfma_f32_16x16x32_bf16(af[mi][ks], bf[ni][ks], acc[mi][ni], 0, 0, 0);
    __builtin_amdgcn_s_setprio(0);

    // ---- P2: wait S2(kt) (S1(kt+1) stays in flight); read A-hi; issue S2(kt+1); MFMA hi ----
    asm volatile("s_waitcnt vmcnt(5)" ::: "memory");
    __builtin_amdgcn_s_barrier();
#pragma unroll
    for (int mi = 0; mi < 4; ++mi)
#pragma unroll
      for (int ks = 0; ks < 2; ++ks)
        af[mi][ks] = *(const short8*)(At + (wm * 128 + 64 + mi * 16 + lr) * 64 + ((ks * 32 + lg * 8) ^ cswz));
    STAGE_S2(ktn, cur ^ 1);
    __builtin_amdgcn_s_barrier();
    __builtin_amdgcn_s_setprio(1);
#pragma unroll
    for (int mi = 0; mi < 4; ++mi)
#pragma unroll
      for (int ni = 0; ni < 3; ++ni)
#pragma unroll
        for (int ks = 0; ks < 2; ++ks)
          acc[4 + mi][ni] = __builtin_amdgcn_mfma_f32_16x16x32_bf16(af[mi][ks], bf[ni][ks], acc[4 + mi][ni], 0, 0, 0);
    __builtin_amdgcn_s_setprio(0);
  }
#undef STAGE_S1
#undef STAGE_S2
  asm volatile("s_waitcnt vmcnt(0)" ::: "memory");  // drain dummy stage before epilogue

  // epilogue: bias + per-ni q/k/v routing (16-col lane groups are 16-aligned; 2048 % 16 == 0
  // so a group never straddles the q/k/v boundary -> dst uniform per group)
#pragma unroll
  for (int ni = 0; ni < 3; ++ni) {
    int ncol = nb + wn * 48 + ni * 16 + lr;
    u16* dst = (ncol < 2048) ? qb : (ncol < 4096 ? kbuf : vbuf);
    int nmod = ncol & 2047;
    float bv = bias[ncol];
#pragma unroll
    for (int m = 0; m < 8; ++m) {
#pragma unroll
      for (int r = 0; r < 4; ++r) {
        int mrow = mb + wm * 128 + m * 16 + lg * 4 + r;
        dst[(size_t)mrow * 2048 + nmod] = f2b(acc[m][ni][r] + bv);
      }
    }
  }
}

// ---------------- V transpose + column partial sums ----------------
__global__ __launch_bounds__(256) void k_vtrans(const u16* __restrict__ v, u16* __restrict__ vt,
                                                float* __restrict__ part) {
  __shared__ u16 L[128 * 136];
  __shared__ float Ls2[256];
  const int t = threadIdx.x;
  const int bh = blockIdx.y, sc = blockIdx.x;  // sc: 128-row s-chunk, 0..15
  const size_t base = (size_t)bh * 262144;
#pragma unroll
  for (int it = 0; it < 8; ++it) {
    int chunk = it * 256 + t;
    int s = chunk >> 4, d8 = (chunk & 15) * 8;
    *(short8*)(L + s * 136 + d8) = *(const short8*)(v + base + (size_t)(sc * 128 + s) * 128 + d8);
  }
  __syncthreads();
#pragma unroll
  for (int it = 0; it < 8; ++it) {
    int chunk = it * 256 + t;
    int dh = chunk >> 4, s8 = (chunk & 15) * 8;
    short8 o;
#pragma unroll
    for (int e = 0; e < 8; ++e) o[e] = (short)L[(s8 + e) * 136 + dh];
    *(short8*)(vt + base + (size_t)dh * 2048 + sc * 128 + s8) = o;
  }
  {
    const int dh = t & 127, seg = t >> 7;
    float ps = 0.f;
#pragma unroll 8
    for (int i = 0; i < 64; ++i) ps += b2f(L[(seg * 64 + i) * 136 + dh]);
    Ls2[t] = ps;
    __syncthreads();
    if (t < 128) part[((size_t)bh * 16 + sc) * 128 + t] = Ls2[t] + Ls2[t + 128];
  }
}

// ---------------- flash attention: async global_load_lds staging + T2-swizzled unpadded LDS ----------------
// R17: staging via global_load_lds (8 issue-only instrs/thread; no reg round-trip, no ds_writes)
// with PRE-SWIZZLED GLOBAL SOURCE (m173 / rule #21): linear LDS dest chunk l holds source
// col-chunk (l ^ (row&7)); reads apply the same XOR -> conflict-free b128 despite 256B/128B
// row strides.  Unpadded LDS = 40960 B -> exactly 4 blocks/CU (was 3).  VGPR stays ~80
// ((256,3) bound, NOT (256,4) which caused R15's spill).  Swizzle involution correctness
// was verified in R15 (absmax unchanged).  Everything else = R9 structure.
__global__ __launch_bounds__(256, 3) void k_attn(const u16* __restrict__ qb,
                                                 const u16* __restrict__ kb,
                                                 const u16* __restrict__ vt,
                                                 const float* __restrict__ part,
                                                 float* __restrict__ out) {
  __shared__ u16 Ks[64 * 128];   // [sk][d], swizzled, no pad
  __shared__ u16 Vs[128 * 64];   // V^T [dh][sk], swizzled, no pad
  __shared__ u16 Ps[4][16 * 64]; // per-wave P [qrow][sk], swizzled, no pad
  const int t = threadIdx.x;
  const int ln = t & 63, wv = t >> 6;
  const int lr = ln & 15, lg = ln >> 4;
  const int lr7 = lr & 7;
  const int L = blockIdx.y * 32 + blockIdx.x;      // launched linear id (x fastest), 0..1023
  const int wl = (L & 7) * 128 + (L >> 3);         // bijective XCD-aware remap (1024 blocks)
  const int bh = wl >> 5;                          // 4 heads per XCD chunk of 128 blocks
  const int qt = 31 - (wl & 31);                   // long strips first in dispatch order
  const size_t base = (size_t)bh * 262144;  // contiguous [2048][128] per head
  const u16* Qh = qb + base;
  const u16* Kh = kb + base;
  const u16* Vth = vt + base;
  float* Oh = out + base;
  const int qs = qt * 64;

  short8 qf[4];
  {
    int qr = qs + wv * 16 + lr;
#pragma unroll
    for (int ks = 0; ks < 4; ++ks)
      qf[ks] = *(const short8*)(Qh + (size_t)qr * 128 + ks * 32 + lg * 8);
  }
  float lsum[4] = {0.f, 0.f, 0.f, 0.f};  // lane-local partial row-sums
  f32x4 acc[8];
  const f32x4 fz = {0.f, 0.f, 0.f, 0.f};
#pragma unroll
  for (int oj = 0; oj < 8; ++oj) acc[oj] = fz;

  // per-lane staging chunk coords (chunk = it*256 + wv*64 + ln; dest is linear chunk order)
  u16* Pw = &Ps[wv][0];
  const int nkt = qt + 1;
  for (int kt = 0; kt < nkt; ++kt) {
    // stage K [64][128]: dest chunk l=(sk,c8) <- source col-chunk c8^(sk&7)  (async, issue-only)
#pragma unroll
    for (int it = 0; it < 4; ++it) {
      int chunk = it * 256 + wv * 64 + ln;
      int sk = chunk >> 4, c8 = (chunk & 15) ^ (sk & 7);
      __builtin_amdgcn_global_load_lds(
          (const __attribute__((address_space(1))) void*)(Kh + (size_t)(kt * 64 + sk) * 128 + c8 * 8),
          (__attribute__((address_space(3))) void*)(Ks + (size_t)(it * 256 + wv * 64) * 8),
          16, 0, 0);
    }
    // stage V^T [128][64]: dest chunk l=(dh,c8) <- source col-chunk c8^(dh&7)
#pragma unroll
    for (int it = 0; it < 4; ++it) {
      int chunk = it * 256 + wv * 64 + ln;
      int dh = chunk >> 3, c8 = (chunk & 7) ^ (dh & 7);
      __builtin_amdgcn_global_load_lds(
          (const __attribute__((address_space(1))) void*)(Vth + (size_t)dh * 2048 + kt * 64 + c8 * 8),
          (__attribute__((address_space(3))) void*)(Vs + (size_t)(it * 256 + wv * 64) * 8),
          16, 0, 0);
    }
    __syncthreads();  // drains vmcnt -> staged tile visible

    f32x4 s[4];
#pragma unroll
    for (int ni = 0; ni < 4; ++ni) s[ni] = fz;
#pragma unroll
    for (int ks = 0; ks < 4; ++ks) {
#pragma unroll
      for (int ni = 0; ni < 4; ++ni) {
        short8 kf = *(const short8*)(Ks + (ni * 16 + lr) * 128 + ((ks * 4 + lg) ^ lr7) * 8);
        s[ni] = __builtin_amdgcn_mfma_f32_16x16x32_bf16(qf[ks], kf, s[ni], 0, 0, 0);
      }
    }
    if (kt == qt) {  // diagonal tile: mask col >= row (diagonal included)
#pragma unroll
      for (int ni = 0; ni < 4; ++ni) {
        int col = kt * 64 + ni * 16 + lr;
#pragma unroll
        for (int r = 0; r < 4; ++r) {
          int row = qs + wv * 16 + lg * 4 + r;
          if (col >= row) s[ni][r] = NEGR;
        }
      }
    }
#pragma unroll
    for (int ni = 0; ni < 4; ++ni)
#pragma unroll
      for (int r = 0; r < 4; ++r) {
        u16 h = f2b(exp2f(s[ni][r] * CSL));
        int pr = lg * 4 + r, pc = ni * 16 + lr;
        Pw[pr * 64 + ((pc >> 3) ^ (pr & 7)) * 8 + (pc & 7)] = h;
        lsum[r] += b2f(h);   // denominator from the same rounded weights PV uses
      }
#pragma unroll
    for (int ks2 = 0; ks2 < 2; ++ks2) {
      short8 pa = *(const short8*)(Pw + lr * 64 + ((ks2 * 4 + lg) ^ lr7) * 8);
#pragma unroll
      for (int oj = 0; oj < 8; ++oj) {
        short8 vf = *(const short8*)(Vs + (oj * 16 + lr) * 64 + ((ks2 * 4 + lg) ^ lr7) * 8);
        acc[oj] = __builtin_amdgcn_mfma_f32_16x16x32_bf16(pa, vf, acc[oj], 0, 0, 0);
      }
    }
    __syncthreads();  // all waves done reading before next tile's staging overwrites
  }

  // epilogue: single cross-lane reduction of the row-sums, then divide.
  float rl[4];
#pragma unroll
  for (int r = 0; r < 4; ++r) {
    float sa = lsum[r];
#pragma unroll
    for (int d = 1; d < 16; d <<= 1) sa += __shfl_xor(sa, d, 64);
    rl[r] = 1.0f / sa;  // row 0 gives inf; overwritten analytically below
  }
#pragma unroll
  for (int oj = 0; oj < 8; ++oj)
#pragma unroll
    for (int r = 0; r < 4; ++r) {
      int row = qs + wv * 16 + lg * 4 + r;
      float val = acc[oj][r] * rl[r];
      if (qt == 0 && wv == 0 && lg == 0 && r == 0) {
        float vs = 0.f;
#pragma unroll
        for (int sc = 0; sc < 16; ++sc) vs += part[(size_t)bh * 2048 + sc * 128 + oj * 16 + lr];
        val = vs * (1.0f / 2048.0f);
      }
      Oh[(size_t)row * 128 + oj * 16 + lr] = val;
    }
}

extern "C" void kernel_launch(void* const* d_in, const int* in_sizes, int n_in,
                              void* d_out, int out_size, void* d_ws, size_t ws_size,
                              hipStream_t stream) {
  (void)in_sizes; (void)n_in; (void)out_size; (void)ws_size;
  const float* q_in = (const float*)d_in[0];
  const float* W = (const float*)d_in[3];
  const float* bias = (const float*)d_in[4];
  float* out = (float*)d_out;

  // workspace layout (bf16 elements unless noted); total ~109.3 MB
  u16* qbf = (u16*)d_ws;                      // 4096*2048
  u16* wtb = qbf + (size_t)4096 * 2048;       // 6144*2048
  u16* qb  = wtb + (size_t)6144 * 2048;       // 4096*2048
  u16* kbf = qb  + (size_t)4096 * 2048;       // 4096*2048
  u16* vbf = kbf + (size_t)4096 * 2048;       // 4096*2048
  u16* vt  = vbf + (size_t)4096 * 2048;       // 4096*2048
  float* part = (float*)(vt + (size_t)4096 * 2048);  // [32][16][128] f32 col-chunk sums

  k_cast_fused<<<7168, 256, 0, stream>>>(q_in, qbf, W, wtb);
  k_gemm256<<<512, 512, 0, stream>>>(qbf, wtb, bias, qb, kbf, vbf);
  k_vtrans<<<dim3(16, 32), 256, 0, stream>>>(vbf, vt, part);
  k_attn<<<dim3(32, 32), 256, 0, stream>>>(qb, kbf, vt, part, out);
}

// Round 18
// 218.310 us; speedup vs baseline: 1.2533x; 1.0066x over previous
//
#include <hip/hip_runtime.h>
#include <hip/hip_bf16.h>
#include <stdint.h>

typedef unsigned short u16;
typedef short short8 __attribute__((ext_vector_type(8)));
typedef short short4v __attribute__((ext_vector_type(4)));
typedef float f32x4 __attribute__((ext_vector_type(4)));

// scale folded into exp2: (1/sqrt(128)) * log2(e)
#define CSL (0.08838834764831845f * 1.4426950408889634f)
#define NEGR -1.0e13f   // raw-score mask value; *CSL -> -1.27e12 -> exp2 -> exactly 0

// B=2, S=2048, D=2048, H=16, DH=128.  M = B*S = 4096, N3 = 3*D = 6144, K = 2048.

__device__ __forceinline__ u16 f2b(float f) {
  union { float f; unsigned int u; } c; c.f = f;
  unsigned int u = c.u;
  u += 0x7fffu + ((u >> 16) & 1u);   // RNE; inputs are finite
  return (u16)(u >> 16);
}
__device__ __forceinline__ float b2f(u16 h) {
  union { float f; unsigned int u; } c; c.u = ((unsigned int)h) << 16;
  return c.f;
}

// ---------------- fused input casts: query f32->bf16 (blocks 0..4095) and
// W [2048][6144] f32 -> Wt [6144][2048] bf16 transpose-cast (blocks 4096..7167) ----------------
__global__ __launch_bounds__(256) void k_cast_fused(const float* __restrict__ q_in,
                                                    u16* __restrict__ qbf,
                                                    const float* __restrict__ W,
                                                    u16* __restrict__ Wt) {
  __shared__ u16 L[64 * 68];
  const int t = threadIdx.x;
  const int b = blockIdx.x;
  if (b < 4096) {
    size_t idx = ((size_t)b * 256 + t) * 8;
    float4 f0 = *(const float4*)(q_in + idx);
    float4 f1 = *(const float4*)(q_in + idx + 4);
    short8 o;
    o[0] = (short)f2b(f0.x); o[1] = (short)f2b(f0.y); o[2] = (short)f2b(f0.z); o[3] = (short)f2b(f0.w);
    o[4] = (short)f2b(f1.x); o[5] = (short)f2b(f1.y); o[6] = (short)f2b(f1.z); o[7] = (short)f2b(f1.w);
    *(short8*)(qbf + idx) = o;
    return;
  }
  const int wb = b - 4096;                 // 0..3071
  const int nb = (wb % 96) * 64;           // n base (0..6143)
  const int kb = (wb / 96) * 64;           // k base (0..2047)
#pragma unroll
  for (int it = 0; it < 4; ++it) {
    int idx = it * 1024 + t * 4;
    int r = idx >> 6, c = idx & 63;
    float4 f = *(const float4*)(W + (size_t)(kb + r) * 6144 + nb + c);
    L[r * 68 + c + 0] = f2b(f.x);
    L[r * 68 + c + 1] = f2b(f.y);
    L[r * 68 + c + 2] = f2b(f.z);
    L[r * 68 + c + 3] = f2b(f.w);
  }
  __syncthreads();
#pragma unroll
  for (int it = 0; it < 4; ++it) {
    int idx = it * 1024 + t * 4;
    int i = idx >> 6, j = idx & 63;
    short4v o;
#pragma unroll
    for (int e = 0; e < 4; ++e) o[e] = (short)L[(j + e) * 68 + i];
    *(short4v*)(Wt + (size_t)(nb + i) * 2048 + kb + j) = o;
  }
}

// ---------------- QKV GEMM, 128x192 tile, 2 BLOCKS/CU (cross-block pipe overlap) ----------------
// R18: 1024 blocks (32m x 32n), 512 thr = 8 waves (2M x 4N -> wave tile 64x48, acc[4][3]),
// BK=64, LDS 80 KiB/block dbuf -> EXACTLY 2 blocks/CU (163840 B).  While one block's waves
// sit in read/barrier phases, the co-resident block's waves feed the MFMA pipe (m114/m97
// mechanism) — the overlap the 1-block/CU 256x192 structure could not express.
// Verified components kept: T2 swizzle (conflicts=0), counted vmcnt (stage kt+1's 5 clusters
// at tile top, vmcnt(5) drains kt only, dummy last stage), supertile XCD map (16m x 8n per
// XCD, m-fastest), launch_bounds(512,4) caps VGPR at 128.
__global__ __launch_bounds__(512, 4) void k_gemm128(const u16* __restrict__ A,
                                                    const u16* __restrict__ Bt,
                                                    const float* __restrict__ bias,
                                                    u16* __restrict__ qb,
                                                    u16* __restrict__ kbuf,
                                                    u16* __restrict__ vbuf) {
  __shared__ u16 As[2][8192];    // [dbuf][128 rows x 64 el], swizzled
  __shared__ u16 Bs[2][12288];   // [dbuf][192 rows x 64 el], swizzled
  const int t = threadIdx.x;
  const int ln = t & 63, w = t >> 6;
  const int lr = ln & 15, lg = ln >> 4;
  const int wm = w >> 2, wn = w & 3;           // 2 x 4 wave grid (wave tile 64x48)
  const int Lid = blockIdx.x;                  // 0..1023
  const int xcd = Lid & 7, l = Lid >> 3;       // 128 blocks per XCD
  const int mt = (xcd & 1) * 16 + (l & 15);    // supertile: 16m x 8n per XCD, m-fastest
  const int nt = (xcd >> 1) * 8 + (l >> 4);
  const int mb = mt * 128, nb = nt * 192;
  const int cswz = (lr & 7) * 8;               // read-side swizzle (elem)
  const int srow = w * 8 + (ln >> 3);          // staging row within 64-row part (0..63)
  const int scol = ((ln & 7) ^ (ln >> 3)) * 8; // pre-swizzled source col (elem)

  const u16* Abase = A + (size_t)mb * 2048;
  const u16* Bbase = Bt + (size_t)nb * 2048;

  f32x4 acc[4][3] = {};

  // full-tile stage: 2 A parts (128 rows) + 3 B parts (192 rows) = 5 wave-issues
#define STAGE_KT(kt_, buf_)                                                                        \
  do {                                                                                             \
    const u16* as_ = Abase + (size_t)srow * 2048 + (kt_) * 64 + scol;                              \
    const u16* bs_ = Bbase + (size_t)srow * 2048 + (kt_) * 64 + scol;                              \
    _Pragma("unroll")                                                                              \
    for (int p = 0; p < 2; ++p)                                                                    \
      __builtin_amdgcn_global_load_lds(                                                            \
          (const __attribute__((address_space(1))) void*)(as_ + (size_t)p * 64 * 2048),            \
          (__attribute__((address_space(3))) void*)(&As[buf_][p * 4096 + w * 512]), 16, 0, 0);     \
    _Pragma("unroll")                                                                              \
    for (int p = 0; p < 3; ++p)                                                                    \
      __builtin_amdgcn_global_load_lds(                                                            \
          (const __attribute__((address_space(1))) void*)(bs_ + (size_t)p * 64 * 2048),            \
          (__attribute__((address_space(3))) void*)(&Bs[buf_][p * 4096 + w * 512]), 16, 0, 0);     \
  } while (0)

  STAGE_KT(0, 0);
  asm volatile("s_waitcnt vmcnt(0)" ::: "memory");
  __builtin_amdgcn_s_barrier();

  for (int kt = 0; kt < 32; ++kt) {
    const int cur = kt & 1;
    const int ktn = (kt + 1) & 31;   // last iter: dummy re-stage of tile 0 (never read)
    const u16* At = &As[cur][0];
    const u16* Bl = &Bs[cur][0];

    STAGE_KT(ktn, cur ^ 1);                            // +5 in flight for kt+1
    asm volatile("s_waitcnt vmcnt(5)" ::: "memory");   // drain kt's 5; keep kt+1's flying
    __builtin_amdgcn_s_barrier();                      // kt's tile visible to all waves

    short8 af[4][2], bf[3][2];
#pragma unroll
    for (int mi = 0; mi < 4; ++mi)
#pragma unroll
      for (int ks = 0; ks < 2; ++ks)
        af[mi][ks] = *(const short8*)(At + (wm * 64 + mi * 16 + lr) * 64 + ((ks * 32 + lg * 8) ^ cswz));
#pragma unroll
    for (int ni = 0; ni < 3; ++ni)
#pragma unroll
      for (int ks = 0; ks < 2; ++ks)
        bf[ni][ks] = *(const short8*)(Bl + (wn * 48 + ni * 16 + lr) * 64 + ((ks * 32 + lg * 8) ^ cswz));

    __builtin_amdgcn_s_setprio(1);
#pragma unroll
    for (int ks = 0; ks < 2; ++ks)
#pragma unroll
      for (int mi = 0; mi < 4; ++mi)
#pragma unroll
        for (int ni = 0; ni < 3; ++ni)
          acc[mi][ni] = __builtin_amdgcn_mfma_f32_16x16x32_bf16(af[mi][ks], bf[ni][ks], acc[mi][ni], 0, 0, 0);
    __builtin_amdgcn_s_setprio(0);
    __builtin_amdgcn_s_barrier();                      // cur-buf reads done before next overwrite
  }
#undef STAGE_KT
  asm volatile("s_waitcnt vmcnt(0)" ::: "memory");  // drain dummy stage before epilogue

  // epilogue: bias + per-(wn,ni) q/k/v routing (16-col lane groups are 16-aligned; 2048 % 16 == 0
  // so a group never straddles the q/k/v boundary -> dst uniform per group)
#pragma unroll
  for (int ni = 0; ni < 3; ++ni) {
    int ncol = nb + wn * 48 + ni * 16 + lr;
    u16* dst = (ncol < 2048) ? qb : (ncol < 4096 ? kbuf : vbuf);
    int nmod = ncol & 2047;
    float bv = bias[ncol];
#pragma unroll
    for (int mi = 0; mi < 4; ++mi) {
#pragma unroll
      for (int r = 0; r < 4; ++r) {
        int mrow = mb + wm * 64 + mi * 16 + lg * 4 + r;
        dst[(size_t)mrow * 2048 + nmod] = f2b(acc[mi][ni][r] + bv);
      }
    }
  }
}

// ---------------- V transpose + column partial sums ----------------
__global__ __launch_bounds__(256) void k_vtrans(const u16* __restrict__ v, u16* __restrict__ vt,
                                                float* __restrict__ part) {
  __shared__ u16 L[128 * 136];
  __shared__ float Ls2[256];
  const int t = threadIdx.x;
  const int bh = blockIdx.y, sc = blockIdx.x;  // sc: 128-row s-chunk, 0..15
  const size_t base = (size_t)bh * 262144;
#pragma unroll
  for (int it = 0; it < 8; ++it) {
    int chunk = it * 256 + t;
    int s = chunk >> 4, d8 = (chunk & 15) * 8;
    *(short8*)(L + s * 136 + d8) = *(const short8*)(v + base + (size_t)(sc * 128 + s) * 128 + d8);
  }
  __syncthreads();
#pragma unroll
  for (int it = 0; it < 8; ++it) {
    int chunk = it * 256 + t;
    int dh = chunk >> 4, s8 = (chunk & 15) * 8;
    short8 o;
#pragma unroll
    for (int e = 0; e < 8; ++e) o[e] = (short)L[(s8 + e) * 136 + dh];
    *(short8*)(vt + base + (size_t)dh * 2048 + sc * 128 + s8) = o;
  }
  {
    const int dh = t & 127, seg = t >> 7;
    float ps = 0.f;
#pragma unroll 8
    for (int i = 0; i < 64; ++i) ps += b2f(L[(seg * 64 + i) * 136 + dh]);
    Ls2[t] = ps;
    __syncthreads();
    if (t < 128) part[((size_t)bh * 16 + sc) * 128 + t] = Ls2[t] + Ls2[t + 128];
  }
}

// ---------------- flash attention: async global_load_lds staging + T2-swizzled unpadded LDS ----------------
// (exact R17 version — measured ~67 us)
__global__ __launch_bounds__(256, 3) void k_attn(const u16* __restrict__ qb,
                                                 const u16* __restrict__ kb,
                                                 const u16* __restrict__ vt,
                                                 const float* __restrict__ part,
                                                 float* __restrict__ out) {
  __shared__ u16 Ks[64 * 128];   // [sk][d], swizzled, no pad
  __shared__ u16 Vs[128 * 64];   // V^T [dh][sk], swizzled, no pad
  __shared__ u16 Ps[4][16 * 64]; // per-wave P [qrow][sk], swizzled, no pad
  const int t = threadIdx.x;
  const int ln = t & 63, wv = t >> 6;
  const int lr = ln & 15, lg = ln >> 4;
  const int lr7 = lr & 7;
  const int L = blockIdx.y * 32 + blockIdx.x;      // launched linear id (x fastest), 0..1023
  const int wl = (L & 7) * 128 + (L >> 3);         // bijective XCD-aware remap (1024 blocks)
  const int bh = wl >> 5;                          // 4 heads per XCD chunk of 128 blocks
  const int qt = 31 - (wl & 31);                   // long strips first in dispatch order
  const size_t base = (size_t)bh * 262144;  // contiguous [2048][128] per head
  const u16* Qh = qb + base;
  const u16* Kh = kb + base;
  const u16* Vth = vt + base;
  float* Oh = out + base;
  const int qs = qt * 64;

  short8 qf[4];
  {
    int qr = qs + wv * 16 + lr;
#pragma unroll
    for (int ks = 0; ks < 4; ++ks)
      qf[ks] = *(const short8*)(Qh + (size_t)qr * 128 + ks * 32 + lg * 8);
  }
  float lsum[4] = {0.f, 0.f, 0.f, 0.f};  // lane-local partial row-sums
  f32x4 acc[8];
  const f32x4 fz = {0.f, 0.f, 0.f, 0.f};
#pragma unroll
  for (int oj = 0; oj < 8; ++oj) acc[oj] = fz;

  u16* Pw = &Ps[wv][0];
  const int nkt = qt + 1;
  for (int kt = 0; kt < nkt; ++kt) {
    // stage K [64][128]: dest chunk l=(sk,c8) <- source col-chunk c8^(sk&7)  (async, issue-only)
#pragma unroll
    for (int it = 0; it < 4; ++it) {
      int chunk = it * 256 + wv * 64 + ln;
      int sk = chunk >> 4, c8 = (chunk & 15) ^ (sk & 7);
      __builtin_amdgcn_global_load_lds(
          (const __attribute__((address_space(1))) void*)(Kh + (size_t)(kt * 64 + sk) * 128 + c8 * 8),
          (__attribute__((address_space(3))) void*)(Ks + (size_t)(it * 256 + wv * 64) * 8),
          16, 0, 0);
    }
    // stage V^T [128][64]: dest chunk l=(dh,c8) <- source col-chunk c8^(dh&7)
#pragma unroll
    for (int it = 0; it < 4; ++it) {
      int chunk = it * 256 + wv * 64 + ln;
      int dh = chunk >> 3, c8 = (chunk & 7) ^ (dh & 7);
      __builtin_amdgcn_global_load_lds(
          (const __attribute__((address_space(1))) void*)(Vth + (size_t)dh * 2048 + kt * 64 + c8 * 8),
          (__attribute__((address_space(3))) void*)(Vs + (size_t)(it * 256 + wv * 64) * 8),
          16, 0, 0);
    }
    __syncthreads();  // drains vmcnt -> staged tile visible

    f32x4 s[4];
#pragma unroll
    for (int ni = 0; ni < 4; ++ni) s[ni] = fz;
#pragma unroll
    for (int ks = 0; ks < 4; ++ks) {
#pragma unroll
      for (int ni = 0; ni < 4; ++ni) {
        short8 kf = *(const short8*)(Ks + (ni * 16 + lr) * 128 + ((ks * 4 + lg) ^ lr7) * 8);
        s[ni] = __builtin_amdgcn_mfma_f32_16x16x32_bf16(qf[ks], kf, s[ni], 0, 0, 0);
      }
    }
    if (kt == qt) {  // diagonal tile: mask col >= row (diagonal included)
#pragma unroll
      for (int ni = 0; ni < 4; ++ni) {
        int col = kt * 64 + ni * 16 + lr;
#pragma unroll
        for (int r = 0; r < 4; ++r) {
          int row = qs + wv * 16 + lg * 4 + r;
          if (col >= row) s[ni][r] = NEGR;
        }
      }
    }
#pragma unroll
    for (int ni = 0; ni < 4; ++ni)
#pragma unroll
      for (int r = 0; r < 4; ++r) {
        u16 h = f2b(exp2f(s[ni][r] * CSL));
        int pr = lg * 4 + r, pc = ni * 16 + lr;
        Pw[pr * 64 + ((pc >> 3) ^ (pr & 7)) * 8 + (pc & 7)] = h;
        lsum[r] += b2f(h);   // denominator from the same rounded weights PV uses
      }
#pragma unroll
    for (int ks2 = 0; ks2 < 2; ++ks2) {
      short8 pa = *(const short8*)(Pw + lr * 64 + ((ks2 * 4 + lg) ^ lr7) * 8);
#pragma unroll
      for (int oj = 0; oj < 8; ++oj) {
        short8 vf = *(const short8*)(Vs + (oj * 16 + lr) * 64 + ((ks2 * 4 + lg) ^ lr7) * 8);
        acc[oj] = __builtin_amdgcn_mfma_f32_16x16x32_bf16(pa, vf, acc[oj], 0, 0, 0);
      }
    }
    __syncthreads();  // all waves done reading before next tile's staging overwrites
  }

  // epilogue: single cross-lane reduction of the row-sums, then divide.
  float rl[4];
#pragma unroll
  for (int r = 0; r < 4; ++r) {
    float sa = lsum[r];
#pragma unroll
    for (int d = 1; d < 16; d <<= 1) sa += __shfl_xor(sa, d, 64);
    rl[r] = 1.0f / sa;  // row 0 gives inf; overwritten analytically below
  }
#pragma unroll
  for (int oj = 0; oj < 8; ++oj)
#pragma unroll
    for (int r = 0; r < 4; ++r) {
      int row = qs + wv * 16 + lg * 4 + r;
      float val = acc[oj][r] * rl[r];
      if (qt == 0 && wv == 0 && lg == 0 && r == 0) {
        float vs = 0.f;
#pragma unroll
        for (int sc = 0; sc < 16; ++sc) vs += part[(size_t)bh * 2048 + sc * 128 + oj * 16 + lr];
        val = vs * (1.0f / 2048.0f);
      }
      Oh[(size_t)row * 128 + oj * 16 + lr] = val;
    }
}

extern "C" void kernel_launch(void* const* d_in, const int* in_sizes, int n_in,
                              void* d_out, int out_size, void* d_ws, size_t ws_size,
                              hipStream_t stream) {
  (void)in_sizes; (void)n_in; (void)out_size; (void)ws_size;
  const float* q_in = (const float*)d_in[0];
  const float* W = (const float*)d_in[3];
  const float* bias = (const float*)d_in[4];
  float* out = (float*)d_out;

  // workspace layout (bf16 elements unless noted); total ~109.3 MB
  u16* qbf = (u16*)d_ws;                      // 4096*2048
  u16* wtb = qbf + (size_t)4096 * 2048;       // 6144*2048
  u16* qb  = wtb + (size_t)6144 * 2048;       // 4096*2048
  u16* kbf = qb  + (size_t)4096 * 2048;       // 4096*2048
  u16* vbf = kbf + (size_t)4096 * 2048;       // 4096*2048
  u16* vt  = vbf + (size_t)4096 * 2048;       // 4096*2048
  float* part = (float*)(vt + (size_t)4096 * 2048);  // [32][16][128] f32 col-chunk sums

  k_cast_fused<<<7168, 256, 0, stream>>>(q_in, qbf, W, wtb);
  k_gemm128<<<1024, 512, 0, stream>>>(qbf, wtb, bias, qb, kbf, vbf);
  k_vtrans<<<dim3(16, 32), 256, 0, stream>>>(vbf, vt, part);
  k_attn<<<dim3(32, 32), 256, 0, stream>>>(qb, kbf, vt, part, out);
}